// Round 12
// baseline (2005.561 us; speedup 1.0000x reference)
//
#include <hip/hip_runtime.h>
#include <math.h>

// Problem dims
#define Sn 128
#define Bn 16
#define Hn 1024
#define En 512
#define Vn 32000
#define H3 3072

typedef _Float16 h16;
typedef __attribute__((ext_vector_type(4))) _Float16 h16x4;
typedef __attribute__((ext_vector_type(8))) _Float16 h16x8;
typedef __attribute__((ext_vector_type(4))) float f32x4;

// ---------- fused f32 -> fp16 convert for ALL operands (one launch) ----------
#define Q_EMB   4096000
#define Q_WIH0  (Q_EMB + 393216)
#define Q_W1    (Q_WIH0 + 262144)
#define Q_W2    (Q_W1 + 131072)
#define Q_WHH0  (Q_W2 + 786432)
#define Q_WIH1  (Q_WHH0 + 786432)
#define Q_WHH1  (Q_WIH1 + 786432)
#define Q_HID   (Q_WHH1 + 8192)
__global__ __launch_bounds__(256) void cvt_all_k(
    const float* __restrict__ emb, const float* __restrict__ wih0,
    const float* __restrict__ w1, const float* __restrict__ w2,
    const float* __restrict__ whh0, const float* __restrict__ wih1,
    const float* __restrict__ whh1, const float* __restrict__ hid,
    h16* __restrict__ E, h16* __restrict__ A, h16* __restrict__ B1,
    h16* __restrict__ B2, h16* __restrict__ D0, h16* __restrict__ D1,
    h16* __restrict__ D2, h16* __restrict__ HD)
{
  int i = blockIdx.x * 256 + threadIdx.x;
  const float* s; h16* d; int o;
  if      (i < Q_EMB)  { s = emb;  d = E;  o = i; }
  else if (i < Q_WIH0) { s = wih0; d = A;  o = i - Q_EMB; }
  else if (i < Q_W1)   { s = w1;   d = B1; o = i - Q_WIH0; }
  else if (i < Q_W2)   { s = w2;   d = B2; o = i - Q_W1; }
  else if (i < Q_WHH0) { s = whh0; d = D0; o = i - Q_W2; }
  else if (i < Q_WIH1) { s = wih1; d = D1; o = i - Q_WHH0; }
  else if (i < Q_WHH1) { s = whh1; d = D2; o = i - Q_WIH1; }
  else                 { s = hid;  d = HD; o = i - Q_WHH1; }
  float4 v = *(const float4*)(s + (size_t)o * 4);
  h16x4 ov = { (h16)v.x, (h16)v.y, (h16)v.z, (h16)v.w };
  *(h16x4*)(d + (size_t)o * 4) = ov;
}

// ---------- embedding gather -> fp16 X, time-major rows t = s*Bn + b ----------
__global__ void embed_k(const int* __restrict__ trg, const float* __restrict__ emb,
                        h16* __restrict__ Xh) {
  int t = blockIdx.x;
  int s = t >> 4, b = t & 15;
  int tok = trg[b * Sn + s];
  const float* src = emb + (size_t)tok * En;
  int e = threadIdx.x * 4;
  float4 v = *(const float4*)(src + e);
  h16x4 o = { (h16)v.x, (h16)v.y, (h16)v.z, (h16)v.w };
  *(h16x4*)(Xh + (size_t)t * En + e) = o;
}

// ---------- fp16 MFMA GEMM 128x128: C(M,N) = A(M,K) @ B(N,K)^T + bias ----------
// OUT_MODE: 0 f32 row-major; 1 fp16 row-major; 2 f32 remapped (b*128+s);
// 3 = f32 gi-relayout: [colblk16][s][b][gate][16]
template<int OUT_MODE, bool RELU, bool SWZ>
__global__ __launch_bounds__(256) void gemm_bt(
    const h16* __restrict__ A, const h16* __restrict__ B,
    const float* __restrict__ bias, void* __restrict__ C,
    int M, int N, int K)
{
  __shared__ h16 As[128 * 64];
  __shared__ h16 Bs[128 * 64];
  int tid = threadIdx.x;
  int l = tid & 63, wv = tid >> 6;
  int wr = wv >> 1, wc = wv & 1;

  int work = blockIdx.x;
  if (SWZ) { int q = gridDim.x >> 3; work = (work & 7) * q + (work >> 3); }
  int nMp = M >> 7;
  int brow = (work % nMp) << 7;
  int bcol = (work / nMp) << 7;

  f32x4 acc[4][4];
#pragma unroll
  for (int m = 0; m < 4; ++m)
#pragma unroll
    for (int n = 0; n < 4; ++n) acc[m][n] = (f32x4){0.f, 0.f, 0.f, 0.f};

  int nkt = K >> 6;
  for (int kt = 0; kt < nkt; ++kt) {
    const h16* Ag = A + (size_t)brow * K + kt * 64;
    const h16* Bg = B + (size_t)bcol * K + kt * 64;
#pragma unroll
    for (int c = tid; c < 2048; c += 256) {
      int half = c >> 10;
      int cc = c & 1023;
      int row = cc >> 3, slot = cc & 7;
      const h16* src = (half ? Bg : Ag) + (size_t)row * K + slot * 8;
      uint4 v = *(const uint4*)src;
      h16* dst = (half ? Bs : As) + row * 64 + ((slot ^ (row & 7)) << 3);
      *(uint4*)dst = v;
    }
    __syncthreads();
#pragma unroll
    for (int kk = 0; kk < 2; ++kk) {
      h16x8 af[4], bfr[4];
      int rb = wr * 64 + (l & 15);
      int cb2 = wc * 64 + (l & 15);
      int slot = kk * 4 + (l >> 4);
#pragma unroll
      for (int m = 0; m < 4; ++m) {
        int r = rb + m * 16;
        af[m] = *(const h16x8*)&As[r * 64 + ((slot ^ (r & 7)) << 3)];
      }
#pragma unroll
      for (int n = 0; n < 4; ++n) {
        int r = cb2 + n * 16;
        bfr[n] = *(const h16x8*)&Bs[r * 64 + ((slot ^ (r & 7)) << 3)];
      }
#pragma unroll
      for (int m = 0; m < 4; ++m)
#pragma unroll
        for (int n = 0; n < 4; ++n)
          acc[m][n] = __builtin_amdgcn_mfma_f32_16x16x32_f16(af[m], bfr[n], acc[m][n], 0, 0, 0);
    }
    __syncthreads();
  }

#pragma unroll
  for (int m = 0; m < 4; ++m) {
    int row0 = brow + wr * 64 + m * 16 + ((l >> 4) << 2);
#pragma unroll
    for (int n = 0; n < 4; ++n) {
      int col = bcol + wc * 64 + n * 16 + (l & 15);
      float bv = bias ? bias[col] : 0.f;
#pragma unroll
      for (int i = 0; i < 4; ++i) {
        int row = row0 + i;
        float v = acc[m][n][i] + bv;
        if (RELU) v = fmaxf(v, 0.f);
        if (OUT_MODE == 1) {
          ((h16*)C)[(size_t)row * N + col] = (h16)v;
        } else if (OUT_MODE == 2) {
          int rr = ((row & 15) << 7) + (row >> 4);
          ((float*)C)[(size_t)rr * N + col] = v;
        } else if (OUT_MODE == 3) {
          size_t idx = (size_t)((col & 1023) >> 4) * 98304 + (size_t)(row >> 4) * 768
                     + (size_t)(row & 15) * 48 + (col >> 10) * 16 + (col & 15);
          ((float*)C)[idx] = v;
        } else {
          ((float*)C)[(size_t)row * N + col] = v;
        }
      }
    }
  }
}

// ---------- fp16 MFMA GEMM 128Mx256N for the logit projection ----------
__global__ __launch_bounds__(256, 1) void gemm_bt256(
    const h16* __restrict__ A, const h16* __restrict__ B,
    const float* __restrict__ bias, float* __restrict__ C,
    int M, int N, int K)
{
  __shared__ h16 As[128 * 64];
  __shared__ h16 Bs[256 * 64];
  int tid = threadIdx.x;
  int l = tid & 63, wv = tid >> 6;
  int wr = wv >> 1, wc = wv & 1;

  int work = blockIdx.x;
  int q = gridDim.x >> 3; work = (work & 7) * q + (work >> 3);
  int nMp = M >> 7;
  int brow = (work % nMp) << 7;
  int bcol = (work / nMp) << 8;

  f32x4 acc[4][8];
#pragma unroll
  for (int m = 0; m < 4; ++m)
#pragma unroll
    for (int n = 0; n < 8; ++n) acc[m][n] = (f32x4){0.f, 0.f, 0.f, 0.f};

  int nkt = K >> 6;
  for (int kt = 0; kt < nkt; ++kt) {
    const h16* Ag = A + (size_t)brow * K + kt * 64;
    const h16* Bg = B + (size_t)bcol * K + kt * 64;
#pragma unroll
    for (int c = tid; c < 3072; c += 256) {
      int isB = (c >= 1024);
      int cc = isB ? (c - 1024) : c;
      int row = cc >> 3, slot = cc & 7;
      const h16* src = (isB ? Bg : Ag) + (size_t)row * K + slot * 8;
      uint4 v = *(const uint4*)src;
      h16* dst = (isB ? Bs : As) + row * 64 + ((slot ^ (row & 7)) << 3);
      *(uint4*)dst = v;
    }
    __syncthreads();
#pragma unroll
    for (int kk = 0; kk < 2; ++kk) {
      h16x8 af[4], bfr[8];
      int rb = wr * 64 + (l & 15);
      int cb2 = wc * 128 + (l & 15);
      int slot = kk * 4 + (l >> 4);
#pragma unroll
      for (int m = 0; m < 4; ++m) {
        int r = rb + m * 16;
        af[m] = *(const h16x8*)&As[r * 64 + ((slot ^ (r & 7)) << 3)];
      }
#pragma unroll
      for (int n = 0; n < 8; ++n) {
        int r = cb2 + n * 16;
        bfr[n] = *(const h16x8*)&Bs[r * 64 + ((slot ^ (r & 7)) << 3)];
      }
#pragma unroll
      for (int m = 0; m < 4; ++m)
#pragma unroll
        for (int n = 0; n < 8; ++n)
          acc[m][n] = __builtin_amdgcn_mfma_f32_16x16x32_f16(af[m], bfr[n], acc[m][n], 0, 0, 0);
    }
    __syncthreads();
  }

#pragma unroll
  for (int m = 0; m < 4; ++m) {
    int row0 = brow + wr * 64 + m * 16 + ((l >> 4) << 2);
#pragma unroll
    for (int n = 0; n < 8; ++n) {
      int col = bcol + wc * 128 + n * 16 + (l & 15);
      float bv = bias[col];
#pragma unroll
      for (int i = 0; i < 4; ++i) {
        int row = row0 + i;
        int rr = ((row & 15) << 7) + (row >> 4);   // b*128 + s
        C[(size_t)rr * N + col] = acc[m][n][i] + bv;
      }
    }
  }
}

// ---------- persistent dataflow GRU: LDS-resident weights (L0) + LDS h-staging ----------
// 128 blocks x 384 threads (6 waves).
//  blocks [0,64):  layer0, 16 cols each. Waves 0-2 = gates r/z/n (weights in LDS, 96KB);
//                  waves 3-5 help staging only. Wave 2 does the update + publish.
//  blocks [64,128): layer1, 16 cols each. Waves 0-2 = ih r/z/n (A=h0[s-1], LDS-staged);
//                  waves 3-5 = hh r/z/n (A=h1[s-2], LDS-staged); wave 5 updates + publishes.
// Per step: one cooperative 32/64KB h-stage into XOR-swizzled LDS; A and (for L0) B
// fragments read from LDS. Flags: store-only, single poller wave + __syncthreads bcast.
__global__ __launch_bounds__(384, 1) void gru_lds(
    const float* __restrict__ gi2,        // [blk64][s][b][gate][16] relayout
    const float* __restrict__ hidden,
    const h16* __restrict__ hinit16,
    const h16* __restrict__ whh0, const float* __restrict__ bhh0,
    const h16* __restrict__ wih1, const float* __restrict__ bih1,
    const h16* __restrict__ whh1, const float* __restrict__ bhh1,
    h16* __restrict__ h0ring,             // [128][16][1024]
    h16* __restrict__ H1A,                // [128][16][1024]
    int* __restrict__ flags)              // fL0[64]@stride4, fL1[64]@+512
{
  extern __shared__ char dyn[];
  int bid = blockIdx.x;
  int tid = threadIdx.x;
  int w = tid >> 6, l = tid & 63;
  int li = l & 15;
  int b0 = (l >> 4) << 2;

  __threadfence();                        // one-time replay-staleness guard
  int* fL0 = flags;
  int* fL1 = flags + 512;

  if (bid < 64) {
    // ================= layer 0 =================
    h16* Wlds = (h16*)dyn;                // 3 slabs x 16384 h16 (96KB), fragment layout
    h16* sA   = (h16*)(dyn + 98304);      // 16 x 1024 h16 swizzled (32KB)
    float* exch = (float*)(dyn + 131072); // 2 x 256 floats
    int blk = bid, jb = blk << 4;

    // one-time: weight slabs -> LDS (fragment layout, all 6 waves)
    for (int i = tid; i < 6144; i += 384) {
      int g = i >> 11, rem = i & 2047, t = rem >> 6, ll = rem & 63;
      const h16* src = whh0 + ((size_t)((g << 10) + jb + (ll & 15)) << 10)
                     + t * 32 + ((ll >> 4) << 3);
      *(h16x8*)(Wlds + g * 16384 + t * 512 + ll * 8) = *(const h16x8*)src;
    }
    float bN = 0.f, bR = 0.f, bZ = 0.f;
    float hprev[4];
    if (w == 2) {
      bR = bhh0[jb + li]; bZ = bhh0[1024 + jb + li]; bN = bhh0[2048 + jb + li];
#pragma unroll
      for (int i = 0; i < 4; ++i) hprev[i] = hidden[((b0 + i) << 10) + jb + li];
    }

    for (int s = 0; s < Sn; ++s) {
      float gr[4], gz[4], gn[4];
      if (w == 2) {                       // gi prefetch (contiguous 3KB slice)
        const float* gb = gi2 + (size_t)blk * 98304 + (size_t)s * 768;
#pragma unroll
        for (int i = 0; i < 4; ++i) {
          gr[i] = gb[(b0 + i) * 48 + li];
          gz[i] = gb[(b0 + i) * 48 + 16 + li];
          gn[i] = gb[(b0 + i) * 48 + 32 + li];
        }
      }
      if (s > 0 && w == 0) {
        while (__hip_atomic_load(&fL0[l << 2], __ATOMIC_RELAXED, __HIP_MEMORY_SCOPE_AGENT) < s) {}
      }
      __syncthreads();                    // #1 release
      asm volatile("" ::: "memory");
      // cooperative stage: h0[s-1] -> sA (swizzled)
      const h16* hsrc = (s == 0) ? hinit16 : h0ring + (((size_t)(s - 1)) << 14);
#pragma unroll
      for (int i = tid; i < 2048; i += 384) {
        int r = i >> 7, g = i & 127;
        h16x8 v = *(const h16x8*)(hsrc + r * 1024 + g * 8);
        *(h16x8*)(sA + r * 1024 + ((g ^ (r & 7)) << 3)) = v;
      }
      __syncthreads();                    // #2 staged
      f32x4 acc = (f32x4){0.f, 0.f, 0.f, 0.f};
      if (w < 3) {
        const h16* wb = Wlds + w * 16384 + l * 8;
        int r = li;
        f32x4 a0 = (f32x4){0.f, 0.f, 0.f, 0.f};
        f32x4 a1 = (f32x4){0.f, 0.f, 0.f, 0.f};
#pragma unroll
        for (int t = 0; t < 32; t += 2) {
          int g0 = t * 4 + (l >> 4), g1 = (t + 1) * 4 + (l >> 4);
          h16x8 A0 = *(const h16x8*)(sA + r * 1024 + ((g0 ^ (r & 7)) << 3));
          h16x8 A1 = *(const h16x8*)(sA + r * 1024 + ((g1 ^ (r & 7)) << 3));
          h16x8 B0 = *(const h16x8*)(wb + t * 512);
          h16x8 B1v = *(const h16x8*)(wb + (t + 1) * 512);
          a0 = __builtin_amdgcn_mfma_f32_16x16x32_f16(A0, B0, a0, 0, 0, 0);
          a1 = __builtin_amdgcn_mfma_f32_16x16x32_f16(A1, B1v, a1, 0, 0, 0);
        }
        acc = a0 + a1;
        if (w < 2) {
#pragma unroll
          for (int i = 0; i < 4; ++i) exch[w * 256 + ((b0 + i) << 4) + li] = acc[i];
        }
      }
      __syncthreads();                    // #3 exch ready
      if (w == 2) {
#pragma unroll
        for (int i = 0; i < 4; ++i) {
          int e = ((b0 + i) << 4) + li;
          float r = 1.f / (1.f + expf(-(exch[e] + bR + gr[i])));
          float z = 1.f / (1.f + expf(-(exch[256 + e] + bZ + gz[i])));
          float n = tanhf(gn[i] + r * (acc[i] + bN));
          float out = (1.f - z) * n + z * hprev[i];
          hprev[i] = out;
          h16 hv = (h16)out; unsigned short us; __builtin_memcpy(&us, &hv, 2);
          __hip_atomic_store((unsigned short*)h0ring + (((size_t)s) << 14) + ((b0 + i) << 10) + jb + li,
                             us, __ATOMIC_RELAXED, __HIP_MEMORY_SCOPE_AGENT);
        }
        asm volatile("s_waitcnt vmcnt(0)" ::: "memory");
        if (l == 0)
          __hip_atomic_store(&fL0[blk << 2], s + 1, __ATOMIC_RELAXED, __HIP_MEMORY_SCOPE_AGENT);
      }
    }
  } else {
    // ================= layer 1 =================
    h16* sA0 = (h16*)dyn;                 // h0[s-1] swizzled (32KB)
    h16* sA1 = (h16*)(dyn + 32768);       // h1[s-2] swizzled (32KB)
    float* exch = (float*)(dyn + 65536);  // 5 x 256 floats
    int blk = bid - 64, jb = blk << 4;
    int isHH = (w >= 3);
    int gate = isHH ? (w - 3) : w;
    const h16* wsrc = isHH ? whh1 : wih1;
    const h16* wp = wsrc + ((size_t)((gate << 10) + jb + li) << 10) + ((l >> 4) << 3);

    float bIR = 0.f, bIZ = 0.f, bIN = 0.f, bHR = 0.f, bHZ = 0.f, bHN = 0.f;
    float hprev[4];
    if (w == 5) {
      bIR = bih1[jb + li]; bIZ = bih1[1024 + jb + li]; bIN = bih1[2048 + jb + li];
      bHR = bhh1[jb + li]; bHZ = bhh1[1024 + jb + li]; bHN = bhh1[2048 + jb + li];
#pragma unroll
      for (int i = 0; i < 4; ++i) hprev[i] = hidden[16384 + ((b0 + i) << 10) + jb + li];
    }

    for (int s = 1; s <= Sn; ++s) {
      if (w == 0) {
        while (__hip_atomic_load(&fL0[l << 2], __ATOMIC_RELAXED, __HIP_MEMORY_SCOPE_AGENT) < s) {}
      } else if (w == 1 && s >= 2) {
        while (__hip_atomic_load(&fL1[l << 2], __ATOMIC_RELAXED, __HIP_MEMORY_SCOPE_AGENT) < s - 1) {}
      }
      __syncthreads();                    // #1 release
      asm volatile("" ::: "memory");
      const h16* src0 = h0ring + (((size_t)(s - 1)) << 14);
      const h16* src1 = (s == 1) ? hinit16 + 16384 : H1A + (((size_t)(s - 2)) << 14);
#pragma unroll
      for (int i = tid; i < 4096; i += 384) {
        int half = i >> 11, ii = i & 2047;
        int r = ii >> 7, g = ii & 127;
        const h16* sp = half ? src1 : src0;
        h16* dp = half ? sA1 : sA0;
        h16x8 v = *(const h16x8*)(sp + r * 1024 + g * 8);
        *(h16x8*)(dp + r * 1024 + ((g ^ (r & 7)) << 3)) = v;
      }
      __syncthreads();                    // #2 staged
      const h16* sA = isHH ? sA1 : sA0;
      int r = li;
      f32x4 a0 = (f32x4){0.f, 0.f, 0.f, 0.f};
      f32x4 a1 = (f32x4){0.f, 0.f, 0.f, 0.f};
#pragma unroll
      for (int tb = 0; tb < 4; ++tb) {
        h16x8 Bv[8], Av[8];
#pragma unroll
        for (int t = 0; t < 8; ++t) Bv[t] = *(const h16x8*)(wp + (tb * 8 + t) * 32);
#pragma unroll
        for (int t = 0; t < 8; ++t) {
          int g = (tb * 8 + t) * 4 + (l >> 4);
          Av[t] = *(const h16x8*)(sA + r * 1024 + ((g ^ (r & 7)) << 3));
        }
#pragma unroll
        for (int t = 0; t < 8; t += 2) {
          a0 = __builtin_amdgcn_mfma_f32_16x16x32_f16(Av[t], Bv[t], a0, 0, 0, 0);
          a1 = __builtin_amdgcn_mfma_f32_16x16x32_f16(Av[t + 1], Bv[t + 1], a1, 0, 0, 0);
        }
      }
      f32x4 acc = a0 + a1;
      if (w < 5) {
#pragma unroll
        for (int i = 0; i < 4; ++i) exch[w * 256 + ((b0 + i) << 4) + li] = acc[i];
      }
      __syncthreads();                    // #3 exch ready
      if (w == 5) {
#pragma unroll
        for (int i = 0; i < 4; ++i) {
          int e = ((b0 + i) << 4) + li;
          float rr = 1.f / (1.f + expf(-(exch[e] + bIR + exch[768 + e] + bHR)));
          float zz = 1.f / (1.f + expf(-(exch[256 + e] + bIZ + exch[1024 + e] + bHZ)));
          float nn = tanhf(exch[512 + e] + bIN + rr * (acc[i] + bHN));
          float out = (1.f - zz) * nn + zz * hprev[i];
          hprev[i] = out;
          h16 hv = (h16)out; unsigned short us; __builtin_memcpy(&us, &hv, 2);
          __hip_atomic_store((unsigned short*)H1A + (((size_t)(s - 1)) << 14) + ((b0 + i) << 10) + jb + li,
                             us, __ATOMIC_RELAXED, __HIP_MEMORY_SCOPE_AGENT);
        }
        asm volatile("s_waitcnt vmcnt(0)" ::: "memory");
        if (l == 0)
          __hip_atomic_store(&fL1[blk << 2], s, __ATOMIC_RELAXED, __HIP_MEMORY_SCOPE_AGENT);
      }
    }
  }
}

extern "C" void kernel_launch(void* const* d_in, const int* in_sizes, int n_in,
                              void* d_out, int out_size, void* d_ws, size_t ws_size,
                              hipStream_t stream) {
  const float* hidden = (const float*)d_in[0];
  const int*   trg    = (const int*)d_in[1];
  const float* emb    = (const float*)d_in[2];
  const float* w_ih0  = (const float*)d_in[3];
  const float* w_hh0  = (const float*)d_in[4];
  const float* b_ih0  = (const float*)d_in[5];
  const float* b_hh0  = (const float*)d_in[6];
  const float* w_ih1  = (const float*)d_in[7];
  const float* w_hh1  = (const float*)d_in[8];
  const float* b_ih1  = (const float*)d_in[9];
  const float* b_hh1  = (const float*)d_in[10];
  const float* w1     = (const float*)d_in[11];
  const float* b1     = (const float*)d_in[12];
  const float* w2     = (const float*)d_in[13];
  const float* b2     = (const float*)d_in[14];
  const float* b_gen  = (const float*)d_in[15];

  char* ws = (char*)d_ws;
  size_t off = 0;
  float* GI2    = (float*)(ws + off); off += (size_t)64 * 128 * 768 * 4;    // 25.2 MB
  h16* Xh       = (h16*)(ws + off);   off += (size_t)Sn * Bn * En * 2;
  h16* embH     = (h16*)(ws + off);   off += (size_t)Vn * En * 2;
  h16* wih0H    = (h16*)(ws + off);   off += (size_t)H3 * En * 2;
  h16* w1H      = (h16*)(ws + off);   off += (size_t)Hn * Hn * 2;
  h16* w2H      = (h16*)(ws + off);   off += (size_t)En * Hn * 2;
  h16* whh0H    = (h16*)(ws + off);   off += (size_t)H3 * Hn * 2;
  h16* wih1H    = (h16*)(ws + off);   off += (size_t)H3 * Hn * 2;
  h16* whh1H    = (h16*)(ws + off);   off += (size_t)H3 * Hn * 2;
  h16* H1A      = (h16*)(ws + off);   off += (size_t)Sn * Bn * Hn * 2;      // 4.2 MB
  h16* h0ring   = (h16*)(ws + off);   off += (size_t)Sn * Bn * Hn * 2;      // 4.2 MB
  h16* hinit16  = (h16*)(ws + off);   off += (size_t)2 * Bn * Hn * 2;
  int* flags    = (int*)(ws + off);   off += 8192;
  // Tb/Ub alias GI2 (dead after the recurrence)
  h16* Tb = (h16*)GI2;
  h16* Ub = (h16*)((char*)GI2 + (8u << 20));

  // fp16 copies of all operands (one fused launch) + embedding gather
  cvt_all_k<<<28320, 256, 0, stream>>>(emb, w_ih0, w1, w2, w_hh0, w_ih1, w_hh1, hidden,
                                       embH, wih0H, w1H, w2H, whh0H, wih1H, whh1H, hinit16);
  embed_k<<<Sn * Bn, 128, 0, stream>>>(trg, emb, Xh);

  // GI2 = X @ w_ih0^T + b_ih0, written in per-block contiguous relayout (OUT_MODE 3)
  gemm_bt<3, false, true><<<384, 256, 0, stream>>>(Xh, wih0H, b_ih0, GI2, Sn * Bn, H3, En);

  // persistent dataflow recurrence: LDS weights (L0) + LDS h-staging
  (void)hipMemsetAsync(flags, 0, 8192, stream);
  const int LDSZ = 133120;   // L0: 96KB W + 32KB A + 2KB exch
  (void)hipFuncSetAttribute(reinterpret_cast<const void*>(gru_lds),
                            hipFuncAttributeMaxDynamicSharedMemorySize, LDSZ);
  gru_lds<<<128, 384, LDSZ, stream>>>(GI2, hidden, hinit16,
                                      whh0H, b_hh0, wih1H, b_ih1, whh1H, b_hh1,
                                      h0ring, H1A, flags);

  // output head, batched over all 2048 rows
  gemm_bt<1, true,  true><<<128,  256, 0, stream>>>(H1A, w1H, b1, Tb, Sn * Bn, Hn, Hn);
  gemm_bt<1, false, true><<<64,   256, 0, stream>>>(Tb, w2H, b2, Ub, Sn * Bn, En, Hn);
  gemm_bt256<<<2000, 256, 0, stream>>>(Ub, embH, b_gen, (float*)d_out, Sn * Bn, Vn, En);
}

// Round 13
// 1862.992 us; speedup vs baseline: 1.0765x; 1.0765x over previous
//
#include <hip/hip_runtime.h>
#include <math.h>

// Problem dims
#define Sn 128
#define Bn 16
#define Hn 1024
#define En 512
#define Vn 32000
#define H3 3072
#define NL0 32
#define NL1 64

typedef _Float16 h16;
typedef __attribute__((ext_vector_type(4))) _Float16 h16x4;
typedef __attribute__((ext_vector_type(8))) _Float16 h16x8;
typedef __attribute__((ext_vector_type(4))) float f32x4;

// ---------- fused f32 -> fp16 convert for ALL operands (one launch) ----------
#define Q_EMB   4096000
#define Q_WIH0  (Q_EMB + 393216)
#define Q_W1    (Q_WIH0 + 262144)
#define Q_W2    (Q_W1 + 131072)
#define Q_WHH0  (Q_W2 + 786432)
#define Q_WIH1  (Q_WHH0 + 786432)
#define Q_WHH1  (Q_WIH1 + 786432)
#define Q_HID   (Q_WHH1 + 8192)
__global__ __launch_bounds__(256) void cvt_all_k(
    const float* __restrict__ emb, const float* __restrict__ wih0,
    const float* __restrict__ w1, const float* __restrict__ w2,
    const float* __restrict__ whh0, const float* __restrict__ wih1,
    const float* __restrict__ whh1, const float* __restrict__ hid,
    h16* __restrict__ E, h16* __restrict__ A, h16* __restrict__ B1,
    h16* __restrict__ B2, h16* __restrict__ D0, h16* __restrict__ D1,
    h16* __restrict__ D2, h16* __restrict__ HD)
{
  int i = blockIdx.x * 256 + threadIdx.x;
  const float* s; h16* d; int o;
  if      (i < Q_EMB)  { s = emb;  d = E;  o = i; }
  else if (i < Q_WIH0) { s = wih0; d = A;  o = i - Q_EMB; }
  else if (i < Q_W1)   { s = w1;   d = B1; o = i - Q_WIH0; }
  else if (i < Q_W2)   { s = w2;   d = B2; o = i - Q_W1; }
  else if (i < Q_WHH0) { s = whh0; d = D0; o = i - Q_W2; }
  else if (i < Q_WIH1) { s = wih1; d = D1; o = i - Q_WHH0; }
  else if (i < Q_WHH1) { s = whh1; d = D2; o = i - Q_WIH1; }
  else                 { s = hid;  d = HD; o = i - Q_WHH1; }
  float4 v = *(const float4*)(s + (size_t)o * 4);
  h16x4 ov = { (h16)v.x, (h16)v.y, (h16)v.z, (h16)v.w };
  *(h16x4*)(d + (size_t)o * 4) = ov;
}

// ---------- embedding gather -> fp16 X, time-major rows t = s*Bn + b ----------
__global__ void embed_k(const int* __restrict__ trg, const float* __restrict__ emb,
                        h16* __restrict__ Xh) {
  int t = blockIdx.x;
  int s = t >> 4, b = t & 15;
  int tok = trg[b * Sn + s];
  const float* src = emb + (size_t)tok * En;
  int e = threadIdx.x * 4;
  float4 v = *(const float4*)(src + e);
  h16x4 o = { (h16)v.x, (h16)v.y, (h16)v.z, (h16)v.w };
  *(h16x4*)(Xh + (size_t)t * En + e) = o;
}

// ---------- fp16 MFMA GEMM 128x128: C(M,N) = A(M,K) @ B(N,K)^T + bias ----------
template<int OUT_MODE, bool RELU, bool SWZ>
__global__ __launch_bounds__(256) void gemm_bt(
    const h16* __restrict__ A, const h16* __restrict__ B,
    const float* __restrict__ bias, void* __restrict__ C,
    int M, int N, int K)
{
  __shared__ h16 As[128 * 64];
  __shared__ h16 Bs[128 * 64];
  int tid = threadIdx.x;
  int l = tid & 63, wv = tid >> 6;
  int wr = wv >> 1, wc = wv & 1;

  int work = blockIdx.x;
  if (SWZ) { int q = gridDim.x >> 3; work = (work & 7) * q + (work >> 3); }
  int nMp = M >> 7;
  int brow = (work % nMp) << 7;
  int bcol = (work / nMp) << 7;

  f32x4 acc[4][4];
#pragma unroll
  for (int m = 0; m < 4; ++m)
#pragma unroll
    for (int n = 0; n < 4; ++n) acc[m][n] = (f32x4){0.f, 0.f, 0.f, 0.f};

  int nkt = K >> 6;
  for (int kt = 0; kt < nkt; ++kt) {
    const h16* Ag = A + (size_t)brow * K + kt * 64;
    const h16* Bg = B + (size_t)bcol * K + kt * 64;
#pragma unroll
    for (int c = tid; c < 2048; c += 256) {
      int half = c >> 10;
      int cc = c & 1023;
      int row = cc >> 3, slot = cc & 7;
      const h16* src = (half ? Bg : Ag) + (size_t)row * K + slot * 8;
      uint4 v = *(const uint4*)src;
      h16* dst = (half ? Bs : As) + row * 64 + ((slot ^ (row & 7)) << 3);
      *(uint4*)dst = v;
    }
    __syncthreads();
#pragma unroll
    for (int kk = 0; kk < 2; ++kk) {
      h16x8 af[4], bfr[4];
      int rb = wr * 64 + (l & 15);
      int cb2 = wc * 64 + (l & 15);
      int slot = kk * 4 + (l >> 4);
#pragma unroll
      for (int m = 0; m < 4; ++m) {
        int r = rb + m * 16;
        af[m] = *(const h16x8*)&As[r * 64 + ((slot ^ (r & 7)) << 3)];
      }
#pragma unroll
      for (int n = 0; n < 4; ++n) {
        int r = cb2 + n * 16;
        bfr[n] = *(const h16x8*)&Bs[r * 64 + ((slot ^ (r & 7)) << 3)];
      }
#pragma unroll
      for (int m = 0; m < 4; ++m)
#pragma unroll
        for (int n = 0; n < 4; ++n)
          acc[m][n] = __builtin_amdgcn_mfma_f32_16x16x32_f16(af[m], bfr[n], acc[m][n], 0, 0, 0);
    }
    __syncthreads();
  }

#pragma unroll
  for (int m = 0; m < 4; ++m) {
    int row0 = brow + wr * 64 + m * 16 + ((l >> 4) << 2);
#pragma unroll
    for (int n = 0; n < 4; ++n) {
      int col = bcol + wc * 64 + n * 16 + (l & 15);
      float bv = bias ? bias[col] : 0.f;
#pragma unroll
      for (int i = 0; i < 4; ++i) {
        int row = row0 + i;
        float v = acc[m][n][i] + bv;
        if (RELU) v = fmaxf(v, 0.f);
        if (OUT_MODE == 1) {
          ((h16*)C)[(size_t)row * N + col] = (h16)v;
        } else if (OUT_MODE == 2) {
          int rr = ((row & 15) << 7) + (row >> 4);
          ((float*)C)[(size_t)rr * N + col] = v;
        } else {
          ((float*)C)[(size_t)row * N + col] = v;
        }
      }
    }
  }
}

// ---------- fp16 MFMA GEMM 128Mx256N for the logit projection ----------
__global__ __launch_bounds__(256, 1) void gemm_bt256(
    const h16* __restrict__ A, const h16* __restrict__ B,
    const float* __restrict__ bias, float* __restrict__ C,
    int M, int N, int K)
{
  __shared__ h16 As[128 * 64];
  __shared__ h16 Bs[256 * 64];
  int tid = threadIdx.x;
  int l = tid & 63, wv = tid >> 6;
  int wr = wv >> 1, wc = wv & 1;

  int work = blockIdx.x;
  int q = gridDim.x >> 3; work = (work & 7) * q + (work >> 3);
  int nMp = M >> 7;
  int brow = (work % nMp) << 7;
  int bcol = (work / nMp) << 8;

  f32x4 acc[4][8];
#pragma unroll
  for (int m = 0; m < 4; ++m)
#pragma unroll
    for (int n = 0; n < 8; ++n) acc[m][n] = (f32x4){0.f, 0.f, 0.f, 0.f};

  int nkt = K >> 6;
  for (int kt = 0; kt < nkt; ++kt) {
    const h16* Ag = A + (size_t)brow * K + kt * 64;
    const h16* Bg = B + (size_t)bcol * K + kt * 64;
#pragma unroll
    for (int c = tid; c < 3072; c += 256) {
      int isB = (c >= 1024);
      int cc = isB ? (c - 1024) : c;
      int row = cc >> 3, slot = cc & 7;
      const h16* src = (isB ? Bg : Ag) + (size_t)row * K + slot * 8;
      uint4 v = *(const uint4*)src;
      h16* dst = (isB ? Bs : As) + row * 64 + ((slot ^ (row & 7)) << 3);
      *(uint4*)dst = v;
    }
    __syncthreads();
#pragma unroll
    for (int kk = 0; kk < 2; ++kk) {
      h16x8 af[4], bfr[8];
      int rb = wr * 64 + (l & 15);
      int cb2 = wc * 128 + (l & 15);
      int slot = kk * 4 + (l >> 4);
#pragma unroll
      for (int m = 0; m < 4; ++m) {
        int r = rb + m * 16;
        af[m] = *(const h16x8*)&As[r * 64 + ((slot ^ (r & 7)) << 3)];
      }
#pragma unroll
      for (int n = 0; n < 8; ++n) {
        int r = cb2 + n * 16;
        bfr[n] = *(const h16x8*)&Bs[r * 64 + ((slot ^ (r & 7)) << 3)];
      }
#pragma unroll
      for (int m = 0; m < 4; ++m)
#pragma unroll
        for (int n = 0; n < 8; ++n)
          acc[m][n] = __builtin_amdgcn_mfma_f32_16x16x32_f16(af[m], bfr[n], acc[m][n], 0, 0, 0);
    }
    __syncthreads();
  }

#pragma unroll
  for (int m = 0; m < 4; ++m) {
    int row0 = brow + wr * 64 + m * 16 + ((l >> 4) << 2);
#pragma unroll
    for (int n = 0; n < 8; ++n) {
      int col = bcol + wc * 128 + n * 16 + (l & 15);
      float bv = bias[col];
#pragma unroll
      for (int i = 0; i < 4; ++i) {
        int row = row0 + i;
        int rr = ((row & 15) << 7) + (row >> 4);   // b*128 + s
        C[(size_t)rr * N + col] = acc[m][n][i] + bv;
      }
    }
  }
}

// ---------- persistent dataflow GRU (round-8 skeleton, trimmed sync) ----------
// 96 blocks x 384 threads (6 waves).
//  blocks [0,32): layer0, 32 cols: waves = 3 gates x 2 col-halves; gate-2 waves update+publish.
//  blocks [32,96): layer1, 16 cols: waves 0-2 ih, 3-5 hh; wave 5 updates+publishes.
// 2 barriers/step: bar-A (poller-wave flag release), bar-B (gate exch). Publish path:
// ring u16 stores -> s_waitcnt vmcnt(0) -> flag store (update wave only, off other waves'
// critical path). Flags contiguous: fL0[64] ints, fL1[64] ints at +64.
__global__ __launch_bounds__(384) void gru_mfma2(
    const float* __restrict__ gi0,
    const float* __restrict__ hidden,
    const h16* __restrict__ hinit16,
    const h16* __restrict__ whh0, const float* __restrict__ bhh0,
    const h16* __restrict__ wih1, const float* __restrict__ bih1,
    const h16* __restrict__ whh1, const float* __restrict__ bhh1,
    h16* __restrict__ h0ring,       // [128][16][1024]
    h16* __restrict__ H1A,          // [128][16][1024]
    int* __restrict__ flags)
{
  __shared__ float exch[5][256];
  int bid = blockIdx.x;
  int tid = threadIdx.x;
  int w = tid >> 6, l = tid & 63;
  int li = l & 15;
  int ko = (l >> 4) << 3;            // k-offset within 32-wide tile (h16 units)
  int b0 = (l >> 4) << 2;            // first batch row of this lane's acc

  __threadfence();                   // one-time replay-staleness guard

  int* fL0 = flags;                  // 64 contiguous ints
  int* fL1 = flags + 64;             // 64 contiguous ints

  if (bid < NL0) {
    // ================= layer 0 =================
    int gate = w >> 1, ch = w & 1;
    int j = bid * 32 + ch * 16 + li;
    h16x8 Bf[32];
    {
      const h16* wp = whh0 + ((size_t)((gate << 10) + j) << 10) + ko;
#pragma unroll
      for (int t = 0; t < 32; ++t) Bf[t] = *(const h16x8*)(wp + t * 32);
    }
    float bR = 0.f, bZ = 0.f, bN = 0.f;
    float hprev[4];
    if (gate == 2) {
      bR = bhh0[j]; bZ = bhh0[1024 + j]; bN = bhh0[2048 + j];
#pragma unroll
      for (int i = 0; i < 4; ++i) hprev[i] = hidden[((b0 + i) << 10) + j];
    }

    for (int s = 0; s < Sn; ++s) {
      // gi prefetch BEFORE poll (latency hides under wait)
      float gr[4], gz[4], gn[4];
      if (gate == 2) {
        const float* gb = gi0 + ((size_t)s << 4) * H3;
#pragma unroll
        for (int i = 0; i < 4; ++i) {
          const float* g = gb + (size_t)(b0 + i) * H3 + j;
          gr[i] = g[0]; gz[i] = g[1024]; gn[i] = g[2048];
        }
      }
      if (s > 0 && w == 0) {
        while (__hip_atomic_load(&fL0[l], __ATOMIC_RELAXED, __HIP_MEMORY_SCOPE_AGENT) < s)
          __builtin_amdgcn_s_sleep(1);
      }
      __syncthreads();               // bar A
      asm volatile("" ::: "memory");
      const h16* hsrc = (s == 0) ? hinit16 : h0ring + (((size_t)(s - 1)) << 14);
      const h16* Ap = hsrc + (li << 10) + ko;
      f32x4 a0 = (f32x4){0.f, 0.f, 0.f, 0.f};
      f32x4 a1 = (f32x4){0.f, 0.f, 0.f, 0.f};
#pragma unroll
      for (int t = 0; t < 32; t += 2) {
        a0 = __builtin_amdgcn_mfma_f32_16x16x32_f16(*(const h16x8*)(Ap + t * 32), Bf[t], a0, 0, 0, 0);
        a1 = __builtin_amdgcn_mfma_f32_16x16x32_f16(*(const h16x8*)(Ap + (t + 1) * 32), Bf[t + 1], a1, 0, 0, 0);
      }
      f32x4 acc = a0 + a1;
      if (w < 4) {
#pragma unroll
        for (int i = 0; i < 4; ++i) exch[w][((b0 + i) << 4) + li] = acc[i];
      }
      __syncthreads();               // bar B
      if (gate == 2) {
#pragma unroll
        for (int i = 0; i < 4; ++i) {
          int e = ((b0 + i) << 4) + li;
          float r = 1.f / (1.f + expf(-(exch[ch][e] + bR + gr[i])));
          float z = 1.f / (1.f + expf(-(exch[2 + ch][e] + bZ + gz[i])));
          float n = tanhf(gn[i] + r * (acc[i] + bN));
          float out = (1.f - z) * n + z * hprev[i];
          hprev[i] = out;
          h16 hv = (h16)out; unsigned short us; __builtin_memcpy(&us, &hv, 2);
          __hip_atomic_store((unsigned short*)h0ring + (((size_t)s) << 14) + ((b0 + i) << 10) + j,
                             us, __ATOMIC_RELAXED, __HIP_MEMORY_SCOPE_AGENT);
        }
        asm volatile("s_waitcnt vmcnt(0)" ::: "memory");
        if (l == 0)
          __hip_atomic_store(&fL0[bid * 2 + ch], s + 1, __ATOMIC_RELAXED, __HIP_MEMORY_SCOPE_AGENT);
      }
    }
  } else {
    // ================= layer 1 =================
    int idx = bid - NL0;             // 0..63
    int j = (idx << 4) + li;
    int isHH = (w >= 3);
    int gate = isHH ? (w - 3) : w;
    h16x8 Bf[32];
    {
      const h16* wsrc = isHH ? whh1 : wih1;
      const h16* wp = wsrc + ((size_t)((gate << 10) + j) << 10) + ko;
#pragma unroll
      for (int t = 0; t < 32; ++t) Bf[t] = *(const h16x8*)(wp + t * 32);
    }
    float bIR = 0.f, bIZ = 0.f, bIN = 0.f, bHR = 0.f, bHZ = 0.f, bHN = 0.f;
    float hprev[4];
    if (w == 5) {
      bIR = bih1[j]; bIZ = bih1[1024 + j]; bIN = bih1[2048 + j];
      bHR = bhh1[j]; bHZ = bhh1[1024 + j]; bHN = bhh1[2048 + j];
#pragma unroll
      for (int i = 0; i < 4; ++i) hprev[i] = hidden[16384 + ((b0 + i) << 10) + j];
    }

    for (int s = 1; s <= Sn; ++s) {
      if (w == 0) {
        while (__hip_atomic_load(&fL0[l], __ATOMIC_RELAXED, __HIP_MEMORY_SCOPE_AGENT) < s)
          __builtin_amdgcn_s_sleep(1);
      } else if (w == 3 && s >= 2) {
        while (__hip_atomic_load(&fL1[l], __ATOMIC_RELAXED, __HIP_MEMORY_SCOPE_AGENT) < s - 1)
          __builtin_amdgcn_s_sleep(1);
      }
      __syncthreads();               // bar A
      asm volatile("" ::: "memory");
      const h16* hsrc = isHH
          ? ((s == 1) ? hinit16 + 16384 : H1A + (((size_t)(s - 2)) << 14))
          : (h0ring + (((size_t)(s - 1)) << 14));
      const h16* Ap = hsrc + (li << 10) + ko;
      f32x4 a0 = (f32x4){0.f, 0.f, 0.f, 0.f};
      f32x4 a1 = (f32x4){0.f, 0.f, 0.f, 0.f};
#pragma unroll
      for (int t = 0; t < 32; t += 2) {
        a0 = __builtin_amdgcn_mfma_f32_16x16x32_f16(*(const h16x8*)(Ap + t * 32), Bf[t], a0, 0, 0, 0);
        a1 = __builtin_amdgcn_mfma_f32_16x16x32_f16(*(const h16x8*)(Ap + (t + 1) * 32), Bf[t + 1], a1, 0, 0, 0);
      }
      f32x4 acc = a0 + a1;
      if (w < 5) {
#pragma unroll
        for (int i = 0; i < 4; ++i) exch[w][((b0 + i) << 4) + li] = acc[i];
      }
      __syncthreads();               // bar B
      if (w == 5) {
#pragma unroll
        for (int i = 0; i < 4; ++i) {
          int e = ((b0 + i) << 4) + li;
          float r = 1.f / (1.f + expf(-(exch[0][e] + bIR + exch[3][e] + bHR)));
          float z = 1.f / (1.f + expf(-(exch[1][e] + bIZ + exch[4][e] + bHZ)));
          float n = tanhf(exch[2][e] + bIN + r * (acc[i] + bHN));
          float out = (1.f - z) * n + z * hprev[i];
          hprev[i] = out;
          h16 hv = (h16)out; unsigned short us; __builtin_memcpy(&us, &hv, 2);
          __hip_atomic_store((unsigned short*)H1A + (((size_t)(s - 1)) << 14) + ((b0 + i) << 10) + j,
                             us, __ATOMIC_RELAXED, __HIP_MEMORY_SCOPE_AGENT);
        }
        asm volatile("s_waitcnt vmcnt(0)" ::: "memory");
        if (l == 0)
          __hip_atomic_store(&fL1[idx], s, __ATOMIC_RELAXED, __HIP_MEMORY_SCOPE_AGENT);
      }
    }
  }
}

extern "C" void kernel_launch(void* const* d_in, const int* in_sizes, int n_in,
                              void* d_out, int out_size, void* d_ws, size_t ws_size,
                              hipStream_t stream) {
  const float* hidden = (const float*)d_in[0];
  const int*   trg    = (const int*)d_in[1];
  const float* emb    = (const float*)d_in[2];
  const float* w_ih0  = (const float*)d_in[3];
  const float* w_hh0  = (const float*)d_in[4];
  const float* b_ih0  = (const float*)d_in[5];
  const float* b_hh0  = (const float*)d_in[6];
  const float* w_ih1  = (const float*)d_in[7];
  const float* w_hh1  = (const float*)d_in[8];
  const float* b_ih1  = (const float*)d_in[9];
  const float* b_hh1  = (const float*)d_in[10];
  const float* w1     = (const float*)d_in[11];
  const float* b1     = (const float*)d_in[12];
  const float* w2     = (const float*)d_in[13];
  const float* b2     = (const float*)d_in[14];
  const float* b_gen  = (const float*)d_in[15];

  char* ws = (char*)d_ws;
  size_t off = 0;
  float* GI0    = (float*)(ws + off); off += (size_t)Sn * Bn * H3 * 4;      // 25.2 MB
  h16* Xh       = (h16*)(ws + off);   off += (size_t)Sn * Bn * En * 2;
  h16* embH     = (h16*)(ws + off);   off += (size_t)Vn * En * 2;
  h16* wih0H    = (h16*)(ws + off);   off += (size_t)H3 * En * 2;
  h16* w1H      = (h16*)(ws + off);   off += (size_t)Hn * Hn * 2;
  h16* w2H      = (h16*)(ws + off);   off += (size_t)En * Hn * 2;
  h16* whh0H    = (h16*)(ws + off);   off += (size_t)H3 * Hn * 2;
  h16* wih1H    = (h16*)(ws + off);   off += (size_t)H3 * Hn * 2;
  h16* whh1H    = (h16*)(ws + off);   off += (size_t)H3 * Hn * 2;
  h16* H1A      = (h16*)(ws + off);   off += (size_t)Sn * Bn * Hn * 2;      // 4.2 MB
  h16* h0ring   = (h16*)(ws + off);   off += (size_t)Sn * Bn * Hn * 2;      // 4.2 MB
  h16* hinit16  = (h16*)(ws + off);   off += (size_t)2 * Bn * Hn * 2;
  int* flags    = (int*)(ws + off);   off += 4096;
  // Tb/Ub alias GI0 (dead after the recurrence)
  h16* Tb = (h16*)GI0;
  h16* Ub = (h16*)((char*)GI0 + (8u << 20));

  // fp16 copies of all operands (one fused launch) + embedding gather
  cvt_all_k<<<28320, 256, 0, stream>>>(emb, w_ih0, w1, w2, w_hh0, w_ih1, w_hh1, hidden,
                                       embH, wih0H, w1H, w2H, whh0H, wih1H, whh1H, hinit16);
  embed_k<<<Sn * Bn, 128, 0, stream>>>(trg, emb, Xh);

  // GI0 = X @ w_ih0^T + b_ih0 (hoisted out of the recurrence)
  gemm_bt<0, false, true><<<384, 256, 0, stream>>>(Xh, wih0H, b_ih0, GI0, Sn * Bn, H3, En);

  // persistent dataflow recurrence (round-8 skeleton, 2 barriers/step, self-publish)
  (void)hipMemsetAsync(flags, 0, 4096, stream);
  gru_mfma2<<<NL0 + NL1, 384, 0, stream>>>(GI0, hidden, hinit16,
                                           whh0H, b_hh0, wih1H, b_ih1, whh1H, b_hh1,
                                           h0ring, H1A, flags);

  // output head, batched over all 2048 rows
  gemm_bt<1, true,  true><<<128,  256, 0, stream>>>(H1A, w1H, b1, Tb, Sn * Bn, Hn, Hn);
  gemm_bt<1, false, true><<<64,   256, 0, stream>>>(Tb, w2H, b2, Ub, Sn * Bn, En, Hn);
  gemm_bt256<<<2000, 256, 0, stream>>>(Ub, embH, b_gen, (float*)d_out, Sn * Bn, Vn, En);
}

// Round 14
// 1372.657 us; speedup vs baseline: 1.4611x; 1.3572x over previous
//
#include <hip/hip_runtime.h>
#include <math.h>

// Problem dims
#define Sn 128
#define Bn 16
#define Hn 1024
#define En 512
#define Vn 32000
#define H3 3072
#define NL0 32
#define NL1 64

typedef _Float16 h16;
typedef __attribute__((ext_vector_type(4))) _Float16 h16x4;
typedef __attribute__((ext_vector_type(8))) _Float16 h16x8;
typedef __attribute__((ext_vector_type(4))) float f32x4;

// ---------- fused f32 -> fp16 convert for ALL operands (one launch) ----------
#define Q_EMB   4096000
#define Q_WIH0  (Q_EMB + 393216)
#define Q_W1    (Q_WIH0 + 262144)
#define Q_W2    (Q_W1 + 131072)
#define Q_WHH0  (Q_W2 + 786432)
#define Q_WIH1  (Q_WHH0 + 786432)
#define Q_WHH1  (Q_WIH1 + 786432)
#define Q_HID   (Q_WHH1 + 8192)
__global__ __launch_bounds__(256) void cvt_all_k(
    const float* __restrict__ emb, const float* __restrict__ wih0,
    const float* __restrict__ w1, const float* __restrict__ w2,
    const float* __restrict__ whh0, const float* __restrict__ wih1,
    const float* __restrict__ whh1, const float* __restrict__ hid,
    h16* __restrict__ E, h16* __restrict__ A, h16* __restrict__ B1,
    h16* __restrict__ B2, h16* __restrict__ D0, h16* __restrict__ D1,
    h16* __restrict__ D2, h16* __restrict__ HD)
{
  int i = blockIdx.x * 256 + threadIdx.x;
  const float* s; h16* d; int o;
  if      (i < Q_EMB)  { s = emb;  d = E;  o = i; }
  else if (i < Q_WIH0) { s = wih0; d = A;  o = i - Q_EMB; }
  else if (i < Q_W1)   { s = w1;   d = B1; o = i - Q_WIH0; }
  else if (i < Q_W2)   { s = w2;   d = B2; o = i - Q_W1; }
  else if (i < Q_WHH0) { s = whh0; d = D0; o = i - Q_W2; }
  else if (i < Q_WIH1) { s = wih1; d = D1; o = i - Q_WHH0; }
  else if (i < Q_WHH1) { s = whh1; d = D2; o = i - Q_WIH1; }
  else                 { s = hid;  d = HD; o = i - Q_WHH1; }
  float4 v = *(const float4*)(s + (size_t)o * 4);
  h16x4 ov = { (h16)v.x, (h16)v.y, (h16)v.z, (h16)v.w };
  *(h16x4*)(d + (size_t)o * 4) = ov;
}

// ---------- embedding gather -> fp16 X, time-major rows t = s*Bn + b ----------
__global__ void embed_k(const int* __restrict__ trg, const float* __restrict__ emb,
                        h16* __restrict__ Xh) {
  int t = blockIdx.x;
  int s = t >> 4, b = t & 15;
  int tok = trg[b * Sn + s];
  const float* src = emb + (size_t)tok * En;
  int e = threadIdx.x * 4;
  float4 v = *(const float4*)(src + e);
  h16x4 o = { (h16)v.x, (h16)v.y, (h16)v.z, (h16)v.w };
  *(h16x4*)(Xh + (size_t)t * En + e) = o;
}

// ---------- fp16 MFMA GEMM 128x128 (for GI0 only) ----------
template<int OUT_MODE, bool RELU, bool SWZ>
__global__ __launch_bounds__(256) void gemm_bt(
    const h16* __restrict__ A, const h16* __restrict__ B,
    const float* __restrict__ bias, void* __restrict__ C,
    int M, int N, int K)
{
  __shared__ h16 As[128 * 64];
  __shared__ h16 Bs[128 * 64];
  int tid = threadIdx.x;
  int l = tid & 63, wv = tid >> 6;
  int wr = wv >> 1, wc = wv & 1;

  int work = blockIdx.x;
  if (SWZ) { int q = gridDim.x >> 3; work = (work & 7) * q + (work >> 3); }
  int nMp = M >> 7;
  int brow = (work % nMp) << 7;
  int bcol = (work / nMp) << 7;

  f32x4 acc[4][4];
#pragma unroll
  for (int m = 0; m < 4; ++m)
#pragma unroll
    for (int n = 0; n < 4; ++n) acc[m][n] = (f32x4){0.f, 0.f, 0.f, 0.f};

  int nkt = K >> 6;
  for (int kt = 0; kt < nkt; ++kt) {
    const h16* Ag = A + (size_t)brow * K + kt * 64;
    const h16* Bg = B + (size_t)bcol * K + kt * 64;
#pragma unroll
    for (int c = tid; c < 2048; c += 256) {
      int half = c >> 10;
      int cc = c & 1023;
      int row = cc >> 3, slot = cc & 7;
      const h16* src = (half ? Bg : Ag) + (size_t)row * K + slot * 8;
      uint4 v = *(const uint4*)src;
      h16* dst = (half ? Bs : As) + row * 64 + ((slot ^ (row & 7)) << 3);
      *(uint4*)dst = v;
    }
    __syncthreads();
#pragma unroll
    for (int kk = 0; kk < 2; ++kk) {
      h16x8 af[4], bfr[4];
      int rb = wr * 64 + (l & 15);
      int cb2 = wc * 64 + (l & 15);
      int slot = kk * 4 + (l >> 4);
#pragma unroll
      for (int m = 0; m < 4; ++m) {
        int r = rb + m * 16;
        af[m] = *(const h16x8*)&As[r * 64 + ((slot ^ (r & 7)) << 3)];
      }
#pragma unroll
      for (int n = 0; n < 4; ++n) {
        int r = cb2 + n * 16;
        bfr[n] = *(const h16x8*)&Bs[r * 64 + ((slot ^ (r & 7)) << 3)];
      }
#pragma unroll
      for (int m = 0; m < 4; ++m)
#pragma unroll
        for (int n = 0; n < 4; ++n)
          acc[m][n] = __builtin_amdgcn_mfma_f32_16x16x32_f16(af[m], bfr[n], acc[m][n], 0, 0, 0);
    }
    __syncthreads();
  }

#pragma unroll
  for (int m = 0; m < 4; ++m) {
    int row0 = brow + wr * 64 + m * 16 + ((l >> 4) << 2);
#pragma unroll
    for (int n = 0; n < 4; ++n) {
      int col = bcol + wc * 64 + n * 16 + (l & 15);
      float bv = bias ? bias[col] : 0.f;
#pragma unroll
      for (int i = 0; i < 4; ++i) {
        int row = row0 + i;
        float v = acc[m][n][i] + bv;
        if (RELU) v = fmaxf(v, 0.f);
        if (OUT_MODE == 1) {
          ((h16*)C)[(size_t)row * N + col] = (h16)v;
        } else {
          ((float*)C)[(size_t)row * N + col] = v;
        }
      }
    }
  }
}

// ================= mega kernel: gru dataflow + progressive head =================

__device__ __forceinline__ void wait_fL1(int* fL1, int target, int tid) {
  if (tid < 64) {
    for (;;) {
      int v = __hip_atomic_load(&fL1[tid << 5], __ATOMIC_RELAXED, __HIP_MEMORY_SCOPE_AGENT);
      if (__all(v >= target)) break;
      __builtin_amdgcn_s_sleep(8);
    }
  }
  __syncthreads();
  asm volatile("" ::: "memory");
}

__device__ __forceinline__ void wait_cnt(int* c, int target, int tid) {
  if (tid == 0) {
    while (__hip_atomic_load(c, __ATOMIC_RELAXED, __HIP_MEMORY_SCOPE_AGENT) < target)
      __builtin_amdgcn_s_sleep(8);
  }
  __syncthreads();
  asm volatile("" ::: "memory");
}

__device__ __forceinline__ void publish_cnt(int* c) {
  __syncthreads();                   // drains each wave's vmem before barrier
  if (threadIdx.x == 0) {
    __threadfence();                 // push block's stores to the coherence point
    atomicAdd(c, 1);
  }
}

// 128x128 head GEMM, 384 threads (waves 4,5 stage-only), C = h16 row-major
__device__ __forceinline__ void gemm_head128(
    const h16* __restrict__ A, const h16* __restrict__ B, const float* __restrict__ bias,
    h16* __restrict__ C, int ldc, int K, int relu, char* dyn, int tid)
{
  h16* As = (h16*)dyn;
  h16* Bs = (h16*)(dyn + 16384);
  int l = tid & 63, wv = tid >> 6;
  int wr = wv >> 1, wc = wv & 1;
  f32x4 acc[4][4];
#pragma unroll
  for (int m = 0; m < 4; ++m)
#pragma unroll
    for (int n = 0; n < 4; ++n) acc[m][n] = (f32x4){0.f, 0.f, 0.f, 0.f};
  int nkt = K >> 6;
  for (int kt = 0; kt < nkt; ++kt) {
    const h16* Ag = A + kt * 64;
    const h16* Bg = B + kt * 64;
    for (int c = tid; c < 2048; c += 384) {
      int half = c >> 10, cc = c & 1023, row = cc >> 3, slot = cc & 7;
      const h16* src = (half ? Bg : Ag) + (size_t)row * K + slot * 8;
      uint4 v = *(const uint4*)src;
      h16* dst = (half ? Bs : As) + row * 64 + ((slot ^ (row & 7)) << 3);
      *(uint4*)dst = v;
    }
    __syncthreads();
    if (wv < 4) {
#pragma unroll
      for (int kk = 0; kk < 2; ++kk) {
        h16x8 af[4], bfr[4];
        int rb = wr * 64 + (l & 15);
        int cb2 = wc * 64 + (l & 15);
        int slot = kk * 4 + (l >> 4);
#pragma unroll
        for (int m = 0; m < 4; ++m) {
          int r = rb + m * 16;
          af[m] = *(const h16x8*)&As[r * 64 + ((slot ^ (r & 7)) << 3)];
        }
#pragma unroll
        for (int n = 0; n < 4; ++n) {
          int r = cb2 + n * 16;
          bfr[n] = *(const h16x8*)&Bs[r * 64 + ((slot ^ (r & 7)) << 3)];
        }
#pragma unroll
        for (int m = 0; m < 4; ++m)
#pragma unroll
          for (int n = 0; n < 4; ++n)
            acc[m][n] = __builtin_amdgcn_mfma_f32_16x16x32_f16(af[m], bfr[n], acc[m][n], 0, 0, 0);
      }
    }
    __syncthreads();
  }
  if (wv < 4) {
#pragma unroll
    for (int m = 0; m < 4; ++m) {
      int row0 = wr * 64 + m * 16 + ((l >> 4) << 2);
#pragma unroll
      for (int n = 0; n < 4; ++n) {
        int col = wc * 64 + n * 16 + (l & 15);
        float bv = bias[col];
#pragma unroll
        for (int i = 0; i < 4; ++i) {
          float v = acc[m][n][i] + bv;
          if (relu) v = fmaxf(v, 0.f);
          C[(size_t)(row0 + i) * ldc + col] = (h16)v;
        }
      }
    }
  }
}

// 128x256 logit GEMM, 384 threads; writes f32 with (b*128+s) row remap
__device__ __forceinline__ void gemm_headlogit(
    const h16* __restrict__ A, const h16* __restrict__ B, const float* __restrict__ bias,
    float* __restrict__ C, int growbase, char* dyn, int tid)
{
  h16* As = (h16*)dyn;                 // 128*64
  h16* Bs = (h16*)(dyn + 16384);       // 256*64
  int l = tid & 63, wv = tid >> 6;
  int wr = wv >> 1, wc = wv & 1;
  f32x4 acc[4][8];
#pragma unroll
  for (int m = 0; m < 4; ++m)
#pragma unroll
    for (int n = 0; n < 8; ++n) acc[m][n] = (f32x4){0.f, 0.f, 0.f, 0.f};
  for (int kt = 0; kt < 8; ++kt) {
    const h16* Ag = A + kt * 64;
    const h16* Bg = B + kt * 64;
    for (int c = tid; c < 3072; c += 384) {
      int isB = (c >= 1024);
      int cc = isB ? (c - 1024) : c;
      int row = cc >> 3, slot = cc & 7;
      const h16* src = (isB ? Bg : Ag) + (size_t)row * 512 + slot * 8;
      uint4 v = *(const uint4*)src;
      h16* dst = (isB ? Bs : As) + row * 64 + ((slot ^ (row & 7)) << 3);
      *(uint4*)dst = v;
    }
    __syncthreads();
    if (wv < 4) {
#pragma unroll
      for (int kk = 0; kk < 2; ++kk) {
        h16x8 af[4], bfr[8];
        int rb = wr * 64 + (l & 15);
        int cb2 = wc * 128 + (l & 15);
        int slot = kk * 4 + (l >> 4);
#pragma unroll
        for (int m = 0; m < 4; ++m) {
          int r = rb + m * 16;
          af[m] = *(const h16x8*)&As[r * 64 + ((slot ^ (r & 7)) << 3)];
        }
#pragma unroll
        for (int n = 0; n < 8; ++n) {
          int r = cb2 + n * 16;
          bfr[n] = *(const h16x8*)&Bs[r * 64 + ((slot ^ (r & 7)) << 3)];
        }
#pragma unroll
        for (int m = 0; m < 4; ++m)
#pragma unroll
          for (int n = 0; n < 8; ++n)
            acc[m][n] = __builtin_amdgcn_mfma_f32_16x16x32_f16(af[m], bfr[n], acc[m][n], 0, 0, 0);
      }
    }
    __syncthreads();
  }
  if (wv < 4) {
#pragma unroll
    for (int m = 0; m < 4; ++m) {
      int row0 = wr * 64 + m * 16 + ((l >> 4) << 2);
#pragma unroll
      for (int n = 0; n < 8; ++n) {
        int col = wc * 128 + n * 16 + (l & 15);
        float bv = bias[col];
#pragma unroll
        for (int i = 0; i < 4; ++i) {
          int grow = growbase + row0 + i;
          int rr = ((grow & 15) << 7) + (grow >> 4);   // b*128 + s
          C[(size_t)rr * Vn + col] = acc[m][n][i] + bv;
        }
      }
    }
  }
}

__global__ __launch_bounds__(384) void mega(
    const float* __restrict__ gi0,
    const float* __restrict__ hidden,
    const h16* __restrict__ hinit16,
    const h16* __restrict__ whh0, const float* __restrict__ bhh0,
    const h16* __restrict__ wih1, const float* __restrict__ bih1,
    const h16* __restrict__ whh1, const float* __restrict__ bhh1,
    h16* __restrict__ h0ring, h16* __restrict__ H1A,
    int* __restrict__ flags,
    const h16* __restrict__ w1H, const float* __restrict__ b1, h16* __restrict__ Tb,
    const h16* __restrict__ w2H, const float* __restrict__ b2, h16* __restrict__ Ub,
    const h16* __restrict__ embH, const float* __restrict__ b_gen,
    float* __restrict__ out)
{
  extern __shared__ char dyn[];
  int bid = blockIdx.x;
  int tid = threadIdx.x;

  __threadfence();                   // replay-staleness guard (inv local caches)

  int* fL0  = flags;                 // 32 flags @ stride 32 ints
  int* fL1  = flags + 1024;          // 64 flags @ stride 32 ints
  int* cnt1 = flags + 3072;          // 16 counters @ stride 8 ints
  int* cnt2 = flags + 3328;          // 16 counters @ stride 8 ints

  if (bid < NL0 + NL1) {
    // ---------------- gru dataflow (round-8 verbatim) ----------------
    float* exch = (float*)dyn;       // 5 x 256 floats
    int w = tid >> 6, l = tid & 63;
    int li = l & 15;
    int ko = (l >> 4) << 3;
    int b0 = (l >> 4) << 2;

    if (bid < NL0) {
      int gate = w >> 1, ch = w & 1;
      int j = bid * 32 + ch * 16 + li;
      h16x8 Bf[32];
      {
        const h16* wp = whh0 + ((size_t)((gate << 10) + j) << 10) + ko;
#pragma unroll
        for (int t = 0; t < 32; ++t) Bf[t] = *(const h16x8*)(wp + t * 32);
      }
      float bR = 0.f, bZ = 0.f, bN = 0.f;
      float hprev[4];
      if (gate == 2) {
        bR = bhh0[j]; bZ = bhh0[1024 + j]; bN = bhh0[2048 + j];
#pragma unroll
        for (int i = 0; i < 4; ++i) hprev[i] = hidden[((b0 + i) << 10) + j];
      }
      for (int s = 0; s < Sn; ++s) {
        if (s > 0) {
          if (w == 0 && l < NL0)
            while (__hip_atomic_load(&fL0[l << 5], __ATOMIC_RELAXED, __HIP_MEMORY_SCOPE_AGENT) < s) {}
          __syncthreads();
          asm volatile("" ::: "memory");
        }
        float gr[4], gz[4], gn[4];
        if (gate == 2) {
          const float* gb = gi0 + ((size_t)s << 4) * H3;
#pragma unroll
          for (int i = 0; i < 4; ++i) {
            const float* g = gb + (size_t)(b0 + i) * H3 + j;
            gr[i] = g[0]; gz[i] = g[1024]; gn[i] = g[2048];
          }
        }
        const h16* hsrc = (s == 0) ? hinit16 : h0ring + (((size_t)(s - 1)) << 14);
        const h16* Ap = hsrc + (li << 10) + ko;
        f32x4 acc = (f32x4){0.f, 0.f, 0.f, 0.f};
#pragma unroll
        for (int t = 0; t < 32; ++t)
          acc = __builtin_amdgcn_mfma_f32_16x16x32_f16(*(const h16x8*)(Ap + t * 32), Bf[t], acc, 0, 0, 0);
        if (w < 4) {
#pragma unroll
          for (int i = 0; i < 4; ++i) exch[w * 256 + ((b0 + i) << 4) + li] = acc[i];
        }
        __syncthreads();
        if (gate == 2) {
#pragma unroll
          for (int i = 0; i < 4; ++i) {
            int e = ((b0 + i) << 4) + li;
            float r = 1.f / (1.f + expf(-(exch[ch * 256 + e] + bR + gr[i])));
            float z = 1.f / (1.f + expf(-(exch[(2 + ch) * 256 + e] + bZ + gz[i])));
            float n = tanhf(gn[i] + r * (acc[i] + bN));
            float o = (1.f - z) * n + z * hprev[i];
            hprev[i] = o;
            h16 hv = (h16)o; unsigned short us; __builtin_memcpy(&us, &hv, 2);
            __hip_atomic_store((unsigned short*)h0ring + (((size_t)s) << 14) + ((b0 + i) << 10) + j,
                               us, __ATOMIC_RELAXED, __HIP_MEMORY_SCOPE_AGENT);
          }
        }
        __syncthreads();
        if (tid == 0)
          __hip_atomic_store(&fL0[bid << 5], s + 1, __ATOMIC_RELAXED, __HIP_MEMORY_SCOPE_AGENT);
      }
    } else {
      int bl = bid - NL0;
      int j = (bl << 4) + li;
      int isHH = (w >= 3);
      int gate = isHH ? (w - 3) : w;
      h16x8 Bf[32];
      {
        const h16* wsrc = isHH ? whh1 : wih1;
        const h16* wp = wsrc + ((size_t)((gate << 10) + j) << 10) + ko;
#pragma unroll
        for (int t = 0; t < 32; ++t) Bf[t] = *(const h16x8*)(wp + t * 32);
      }
      float bIR = 0.f, bIZ = 0.f, bIN = 0.f, bHR = 0.f, bHZ = 0.f, bHN = 0.f;
      float hprev[4];
      if (w == 5) {
        bIR = bih1[j]; bIZ = bih1[1024 + j]; bIN = bih1[2048 + j];
        bHR = bhh1[j]; bHZ = bhh1[1024 + j]; bHN = bhh1[2048 + j];
#pragma unroll
        for (int i = 0; i < 4; ++i) hprev[i] = hidden[16384 + ((b0 + i) << 10) + j];
      }
      for (int s = 1; s <= Sn; ++s) {
        if (w == 0) {
          if (l < NL0)
            while (__hip_atomic_load(&fL0[l << 5], __ATOMIC_RELAXED, __HIP_MEMORY_SCOPE_AGENT) < s) {}
        } else if (w == 1 && s >= 2) {
          while (__hip_atomic_load(&fL1[l << 5], __ATOMIC_RELAXED, __HIP_MEMORY_SCOPE_AGENT) < s) {}
        }
        __syncthreads();
        asm volatile("" ::: "memory");
        const h16* hsrc = isHH
            ? ((s == 1) ? hinit16 + 16384 : H1A + (((size_t)(s - 2)) << 14))
            : (h0ring + (((size_t)(s - 1)) << 14));
        const h16* Ap = hsrc + (li << 10) + ko;
        f32x4 acc = (f32x4){0.f, 0.f, 0.f, 0.f};
#pragma unroll
        for (int t = 0; t < 32; ++t)
          acc = __builtin_amdgcn_mfma_f32_16x16x32_f16(*(const h16x8*)(Ap + t * 32), Bf[t], acc, 0, 0, 0);
        if (w < 5) {
#pragma unroll
          for (int i = 0; i < 4; ++i) exch[w * 256 + ((b0 + i) << 4) + li] = acc[i];
        }
        __syncthreads();
        if (w == 5) {
#pragma unroll
          for (int i = 0; i < 4; ++i) {
            int e = ((b0 + i) << 4) + li;
            float r = 1.f / (1.f + expf(-(exch[e] + bIR + exch[768 + e] + bHR)));
            float z = 1.f / (1.f + expf(-(exch[256 + e] + bIZ + exch[1024 + e] + bHZ)));
            float n = tanhf(exch[512 + e] + bIN + r * (acc[i] + bHN));
            float o = (1.f - z) * n + z * hprev[i];
            hprev[i] = o;
            h16 hv = (h16)o; unsigned short us; __builtin_memcpy(&us, &hv, 2);
            __hip_atomic_store((unsigned short*)H1A + (((size_t)(s - 1)) << 14) + ((b0 + i) << 10) + j,
                               us, __ATOMIC_RELAXED, __HIP_MEMORY_SCOPE_AGENT);
          }
        }
        __syncthreads();
        if (tid == 0)
          __hip_atomic_store(&fL1[bl << 5], s + 1, __ATOMIC_RELAXED, __HIP_MEMORY_SCOPE_AGENT);
      }
    }
    return;
  }

  // ---------------- progressive head ----------------
  int hb = bid - (NL0 + NL1);
  int m = hb / 137;
  int r = hb - m * 137;

  if (r < 8) {
    // MLP1: Tb[128m.., 128r..] = relu(H1A_panel @ w1^T + b1)
    wait_fL1(fL1, 8 * m + 9, tid);
    gemm_head128(H1A + (size_t)(m * 128) * Hn, w1H + (size_t)(r * 128) * Hn,
                 b1 + r * 128, Tb + (size_t)(m * 128) * Hn + r * 128, Hn, Hn, 1, dyn, tid);
    publish_cnt(&cnt1[m << 3]);
  } else if (r < 12) {
    // MLP2: Ub[128m.., 128(r-8)..] = Tb_panel @ w2^T + b2
    int rn = r - 8;
    wait_cnt(&cnt1[m << 3], 8, tid);
    gemm_head128(Tb + (size_t)(m * 128) * Hn, w2H + (size_t)(rn * 128) * Hn,
                 b2 + rn * 128, Ub + (size_t)(m * 128) * En + rn * 128, En, Hn, 0, dyn, tid);
    publish_cnt(&cnt2[m << 3]);
  } else {
    // logit: out rows panel m, cols [256*(r-12) ..)
    int np = r - 12;
    wait_cnt(&cnt2[m << 3], 4, tid);
    gemm_headlogit(Ub + (size_t)(m * 128) * En, embH + (size_t)(np * 256) * En,
                   b_gen + np * 256, out + np * 256, m * 128, dyn, tid);
  }
}

extern "C" void kernel_launch(void* const* d_in, const int* in_sizes, int n_in,
                              void* d_out, int out_size, void* d_ws, size_t ws_size,
                              hipStream_t stream) {
  const float* hidden = (const float*)d_in[0];
  const int*   trg    = (const int*)d_in[1];
  const float* emb    = (const float*)d_in[2];
  const float* w_ih0  = (const float*)d_in[3];
  const float* w_hh0  = (const float*)d_in[4];
  const float* b_ih0  = (const float*)d_in[5];
  const float* b_hh0  = (const float*)d_in[6];
  const float* w_ih1  = (const float*)d_in[7];
  const float* w_hh1  = (const float*)d_in[8];
  const float* b_ih1  = (const float*)d_in[9];
  const float* b_hh1  = (const float*)d_in[10];
  const float* w1     = (const float*)d_in[11];
  const float* b1     = (const float*)d_in[12];
  const float* w2     = (const float*)d_in[13];
  const float* b2     = (const float*)d_in[14];
  const float* b_gen  = (const float*)d_in[15];

  char* ws = (char*)d_ws;
  size_t off = 0;
  float* GI0    = (float*)(ws + off); off += (size_t)Sn * Bn * H3 * 4;      // 25.2 MB
  h16* Xh       = (h16*)(ws + off);   off += (size_t)Sn * Bn * En * 2;
  h16* embH     = (h16*)(ws + off);   off += (size_t)Vn * En * 2;
  h16* wih0H    = (h16*)(ws + off);   off += (size_t)H3 * En * 2;
  h16* w1H      = (h16*)(ws + off);   off += (size_t)Hn * Hn * 2;
  h16* w2H      = (h16*)(ws + off);   off += (size_t)En * Hn * 2;
  h16* whh0H    = (h16*)(ws + off);   off += (size_t)H3 * Hn * 2;
  h16* wih1H    = (h16*)(ws + off);   off += (size_t)H3 * Hn * 2;
  h16* whh1H    = (h16*)(ws + off);   off += (size_t)H3 * Hn * 2;
  h16* H1A      = (h16*)(ws + off);   off += (size_t)Sn * Bn * Hn * 2;      // 4.2 MB
  h16* h0ring   = (h16*)(ws + off);   off += (size_t)Sn * Bn * Hn * 2;      // 4.2 MB
  h16* hinit16  = (h16*)(ws + off);   off += (size_t)2 * Bn * Hn * 2;
  h16* Tb       = (h16*)(ws + off);   off += (size_t)Sn * Bn * Hn * 2;      // 4.2 MB
  h16* Ub       = (h16*)(ws + off);   off += (size_t)Sn * Bn * En * 2;      // 2.1 MB
  int* flags    = (int*)(ws + off);   off += 16384;

  // fp16 copies of all operands (one fused launch) + embedding gather
  cvt_all_k<<<28320, 256, 0, stream>>>(emb, w_ih0, w1, w2, w_hh0, w_ih1, w_hh1, hidden,
                                       embH, wih0H, w1H, w2H, whh0H, wih1H, whh1H, hinit16);
  embed_k<<<Sn * Bn, 128, 0, stream>>>(trg, emb, Xh);

  // GI0 = X @ w_ih0^T + b_ih0 (hoisted out of the recurrence)
  gemm_bt<0, false, true><<<384, 256, 0, stream>>>(Xh, wih0H, b_ih0, GI0, Sn * Bn, H3, En);

  // mega: 96 gru blocks + 2192 head blocks (ordered by M-panel), flag/counter dataflow
  (void)hipMemsetAsync(flags, 0, 16384, stream);
  const int LDSZ = 49152;
  (void)hipFuncSetAttribute(reinterpret_cast<const void*>(mega),
                            hipFuncAttributeMaxDynamicSharedMemorySize, LDSZ);
  mega<<<NL0 + NL1 + 16 * 137, 384, LDSZ, stream>>>(
      GI0, hidden, hinit16, whh0H, b_hh0, wih1H, b_ih1, whh1H, b_hh1,
      h0ring, H1A, flags, w1H, b1, Tb, w2H, b2, Ub, embH, b_gen, (float*)d_out);
}